// Round 3
// baseline (195.710 us; speedup 1.0000x reference)
//
#include <hip/hip_runtime.h>

typedef unsigned short u16;
typedef __attribute__((ext_vector_type(8))) __bf16 bf16x8;
typedef __attribute__((ext_vector_type(4))) float f32x4;

__device__ __forceinline__ u16 f2bf(float f) {
    union { float f; unsigned u; } v; v.f = f;
    unsigned u = v.u;
    u += 0x7FFFu + ((u >> 16) & 1u);
    return (u16)(u >> 16);
}

// async global->LDS copy, 16B per lane (m97 pattern)
typedef const __attribute__((address_space(1))) void GV;
typedef __attribute__((address_space(3))) void LV;
__device__ __forceinline__ void gl2lds16(const void* g, void* l) {
    __builtin_amdgcn_global_load_lds((GV*)g, (LV*)l, 16, 0, 0);
}

// ---------------- fused cast fp32 -> bf16 (x + 4 weights in ONE launch) ----------------
__global__ __launch_bounds__(256) void cast_all(
    const float* __restrict__ x,  const float* __restrict__ Wq,
    const float* __restrict__ Wk, const float* __restrict__ Wv,
    const float* __restrict__ Wp,
    u16* __restrict__ xb, u16* __restrict__ wb, u16* __restrict__ wpb)
{
    int bid = blockIdx.x;
    const float4* s; ushort4* d; int idx;
    if (bid < 6144) {                    // x: 1572864 float4 = 6144 blocks
        s = (const float4*)x; d = (ushort4*)xb; idx = bid * 256 + threadIdx.x;
    } else {                             // weights: 147456 float4 = 576 blocks each
        int t = bid - 6144;
        int w = t / 576;
        idx = (t - w * 576) * 256 + threadIdx.x;
        s = (const float4*)(w == 0 ? Wq : w == 1 ? Wk : w == 2 ? Wv : Wp);
        d = (ushort4*)(w == 3 ? wpb : wb + w * 589824);
    }
    float4 f = s[idx];
    ushort4 o;
    o.x = f2bf(f.x); o.y = f2bf(f.y); o.z = f2bf(f.z); o.w = f2bf(f.w);
    d[idx] = o;
}

// ---------------- GEMM v7: v6 core + XCD-chunked block swizzle (T1) ----------------
// Tiles have 64-elem (128 B) rows. Lane-linear LDS dest (global_load_lds constraint);
// phys 16B chunk p of row r holds LOGICAL chunk p ^ (r&7) -> frag column reads are
// 2-way bank aliased = free (verified SQ_LDS_BANK_CONFLICT=0 rounds 0-2).
__device__ __forceinline__ void stage_g(const u16* src, int k0, u16* lds, int g, int tid) {
    int i = g * 512 + tid;               // 16B chunk id
    int row = i >> 3, p = i & 7;
    int l = p ^ (row & 7);
    gl2lds16(src + (size_t)row * 768 + k0 + l * 8, lds + i * 8);
}
__device__ __forceinline__ const bf16x8* frag64(const u16* lds, int row, int kc) {
    return reinterpret_cast<const bf16x8*>(lds + row * 64 + ((kc ^ (row & 7)) * 8));
}

// 12 K-tiles of 64, ring-3 LDS (A 3x32KB, B 3x16KB = 144KB), prefetch dist 2,
// 2 phases/tile, counted vmcnt(6) at tile boundary (never 0 mid-loop).
__device__ __forceinline__ void kloop256(
    const u16* __restrict__ aSrc, const u16* __restrict__ bSrc,
    u16* As, u16* Bs, f32x4 (&acc)[4][4],
    int tid, int wm, int wn, int quad, int l16)
{
    #pragma unroll
    for (int tt = 0; tt < 2; tt++) {
        #pragma unroll
        for (int g = 0; g < 4; g++) stage_g(aSrc, tt * 64, As + tt * 16384, g, tid);
        #pragma unroll
        for (int g = 0; g < 2; g++) stage_g(bSrc, tt * 64, Bs + tt * 8192, g, tid);
    }
    asm volatile("s_waitcnt vmcnt(6)" ::: "memory");
    __builtin_amdgcn_s_barrier();
    asm volatile("" ::: "memory");

    int buf = 0;
    for (int t = 0; t < 12; t++) {
        const u16* Ab = As + buf * 16384;
        const u16* Bb = Bs + buf * 8192;
        int sb = buf + 2; if (sb >= 3) sb -= 3;
        u16* Asb = As + sb * 16384;
        u16* Bsb = Bs + sb * 8192;
        const bool pf = (t + 2 < 12);
        const int k2 = (t + 2) * 64;

        // ---- phase A (k-half 0) ----
        bf16x8 a[4], b[4];
        #pragma unroll
        for (int mi = 0; mi < 4; mi++) a[mi] = *frag64(Ab, wm * 64 + mi * 16 + l16, quad);
        #pragma unroll
        for (int ni = 0; ni < 4; ni++) b[ni] = *frag64(Bb, wn * 64 + ni * 16 + l16, quad);
        if (pf) {
            stage_g(aSrc, k2, Asb, 0, tid);
            stage_g(aSrc, k2, Asb, 1, tid);
            stage_g(aSrc, k2, Asb, 2, tid);
        }
        __builtin_amdgcn_s_barrier();
        asm volatile("" ::: "memory");
        __builtin_amdgcn_s_setprio(1);
        #pragma unroll
        for (int mi = 0; mi < 4; mi++)
            #pragma unroll
            for (int ni = 0; ni < 4; ni++)
                acc[mi][ni] = __builtin_amdgcn_mfma_f32_16x16x32_bf16(a[mi], b[ni], acc[mi][ni], 0, 0, 0);
        __builtin_amdgcn_s_setprio(0);

        // ---- phase B (k-half 1) ----
        #pragma unroll
        for (int mi = 0; mi < 4; mi++) a[mi] = *frag64(Ab, wm * 64 + mi * 16 + l16, 4 + quad);
        #pragma unroll
        for (int ni = 0; ni < 4; ni++) b[ni] = *frag64(Bb, wn * 64 + ni * 16 + l16, 4 + quad);
        if (pf) {
            stage_g(aSrc, k2, Asb, 3, tid);
            stage_g(bSrc, k2, Bsb, 0, tid);
            stage_g(bSrc, k2, Bsb, 1, tid);
        }
        if (t <= 9)       asm volatile("s_waitcnt vmcnt(6)" ::: "memory");
        else if (t == 10) asm volatile("s_waitcnt vmcnt(0)" ::: "memory");
        __builtin_amdgcn_s_barrier();
        asm volatile("" ::: "memory");
        __builtin_amdgcn_s_setprio(1);
        #pragma unroll
        for (int mi = 0; mi < 4; mi++)
            #pragma unroll
            for (int ni = 0; ni < 4; ni++)
                acc[mi][ni] = __builtin_amdgcn_mfma_f32_16x16x32_bf16(a[mi], b[ni], acc[mi][ni], 0, 0, 0);
        __builtin_amdgcn_s_setprio(0);

        buf++; if (buf == 3) buf = 0;
    }
}

// ---------------- QKV projection GEMM (v7: +XCD swizzle) ----------------
// A = xb [8192][768] bf16, Bm = wb [2304][768] bf16 (Wq|Wk|Wv rows, K-contig)
// out: q,k as [B,H,N,D] bf16 (q scaled by 0.125), v transposed as [B,H,D,N] bf16
__global__ __launch_bounds__(512, 2) void gemm_qkv(
    const u16* __restrict__ A, const u16* __restrict__ Bm,
    u16* __restrict__ qo, u16* __restrict__ ko, u16* __restrict__ vto)
{
    __shared__ u16 As[3][16384];         // 96 KB
    __shared__ u16 Bs[3][8192];          // 48 KB
    const int tid = threadIdx.x;
    const int wave = tid >> 6, lane = tid & 63;
    const int quad = lane >> 4, l16 = lane & 15;
    const int wm = wave >> 1, wn = wave & 1;      // 4M x 2N waves
    // XCD-chunked swizzle (T1): nwg=576, 8 XCDs x 72 blocks; 72 = 4 full
    // A-panels of 18 -> each A-panel is L2-resident on exactly ONE XCD.
    // Bijective since 576 % 8 == 0 (ERRATA #11 guard).
    const int id = blockIdx.x + 18 * blockIdx.y;
    const int nid = (id & 7) * 72 + (id >> 3);
    const int bx = nid % 18, by = nid / 18;
    const int rowBase = by * 256;
    const int colBase = bx * 128;

    f32x4 acc[4][4] = {};
    kloop256(A + (size_t)rowBase * 768, Bm + (size_t)colBase * 768,
             &As[0][0], &Bs[0][0], acc, tid, wm, wn, quad, l16);

    #pragma unroll
    for (int mi = 0; mi < 4; mi++) {
        #pragma unroll
        for (int ni = 0; ni < 4; ni++) {
            int gj = colBase + wn * 64 + ni * 16 + l16;   // 0..2303
            int which = gj / 768;                         // 0=q,1=k,2=v (uniform per tile)
            int r = gj - which * 768;
            int h = r >> 6, d = r & 63;
            int gi0 = rowBase + wm * 64 + mi * 16 + quad * 4;
            int b_ = gi0 >> 10;                           // constant across 4 rows (gi0 % 4 == 0)
            int n0 = gi0 & 1023;
            if (which == 2) {
                // v transposed: 4 consecutive n at fixed d -> one 8B store
                ushort4 pk;
                pk.x = f2bf(acc[mi][ni][0]);
                pk.y = f2bf(acc[mi][ni][1]);
                pk.z = f2bf(acc[mi][ni][2]);
                pk.w = f2bf(acc[mi][ni][3]);
                *reinterpret_cast<ushort4*>(vto + ((size_t)(b_ * 12 + h) * 64 + d) * 1024 + n0) = pk;
            } else {
                float s = (which == 0) ? 0.125f : 1.0f;
                u16* dst = (which == 0 ? qo : ko) + ((size_t)(b_ * 12 + h) * 1024 + n0) * 64 + d;
                #pragma unroll
                for (int rr = 0; rr < 4; rr++)
                    dst[(size_t)rr * 64] = f2bf(acc[mi][ni][rr] * s);
            }
        }
    }
}

// ---------------- fused flash attention (v8: 256-query tiles, 8 waves) ----------------
// q,k: [B,H,N,D] bf16 (q pre-scaled by 0.125), vt: [B,H,D,N] bf16, ao: [B,N,H*D] bf16
// 8 waves x 32 queries = 256 queries/block -> each head's K/V streamed by only
// 4 blocks (was 8): K/V global traffic halves, staging instrs/query halve.
// Per-wave math identical to verified v7. 68 KB LDS -> 2 blocks/CU; grid 384
// blocks = single dispatch round. bh fast => same head -> same XCD (96%8==0).
__global__ __launch_bounds__(512, 4) void attn_fwd(
    const u16* __restrict__ q, const u16* __restrict__ k,
    const u16* __restrict__ vt, u16* __restrict__ ao)
{
    __shared__ u16 Ks[2][4096];      // [buf][row 0..63][chunk_phys 0..7][8 bf16]
    __shared__ u16 Vs[2][4096];
    __shared__ u16 Ps[256][72];
    const int bh = blockIdx.x, qt = blockIdx.y;
    const int b = bh / 12, h = bh - b * 12;
    const int tid = threadIdx.x;
    const int wave = tid >> 6, lane = tid & 63;
    const int quad = lane >> 4, l16 = lane & 15;
    const int swz = l16 & 7;
    u16 (*PsW)[72] = &Ps[wave * 32];

    const u16* qb = q + (size_t)bh * 65536 + ((size_t)qt * 256 + wave * 32) * 64;
    const u16* kb = k + (size_t)bh * 65536;
    const u16* vb = vt + (size_t)bh * 65536;

    // stage one 64-key chunk of K and V^T into LDS buf (8 KB each, swizzled);
    // 512 threads -> exactly one 16B chunk of each per thread.
    auto stage = [&](int buf, int j0) {
        int i = tid;                         // 0..511, 16B each
        int row = i >> 3, cp = i & 7;
        int cl = cp ^ (row & 7);             // logical chunk held in phys slot cp
        gl2lds16((const char*)kb + (size_t)(j0 + row) * 128 + cl * 16,
                 (char*)&Ks[buf][0] + i * 16);
        gl2lds16((const char*)vb + (size_t)row * 2048 + (size_t)j0 * 2 + cl * 16,
                 (char*)&Vs[buf][0] + i * 16);
    };

    stage(0, 0);

    // Q frags (B-operand of S^T): lane l16 = query row, k-dim = ks*32+quad*8
    bf16x8 qf[2][2];
    #pragma unroll
    for (int ni = 0; ni < 2; ni++)
        #pragma unroll
        for (int ks = 0; ks < 2; ks++)
            qf[ni][ks] = *reinterpret_cast<const bf16x8*>(qb + (ni * 16 + l16) * 64 + ks * 32 + quad * 8);

    f32x4 o[2][4] = {};              // [query tile][d tile]
    float lsum[2] = {0.f, 0.f};      // per-lane partial row sums (query = ni*16+l16)

    __syncthreads();                 // staging of chunk 0 complete (vmcnt(0) at barrier)

    int buf = 0;
    for (int j0 = 0; j0 < 1024; j0 += 64) {
        if (j0 + 64 < 1024) stage(buf ^ 1, j0 + 64);   // async prefetch next chunk

        // S^T = K @ Q^T : C rows = keys (quad*4+reg), C cols = queries (l16)
        f32x4 s[4][2] = {};
        #pragma unroll
        for (int ks = 0; ks < 2; ks++) {
            bf16x8 kf[4];
            #pragma unroll
            for (int mi = 0; mi < 4; mi++) {
                int row = mi * 16 + l16;
                int ch = (ks * 4 + quad) ^ swz;
                kf[mi] = *reinterpret_cast<const bf16x8*>(&Ks[buf][row * 64 + ch * 8]);
            }
            #pragma unroll
            for (int mi = 0; mi < 4; mi++)
                #pragma unroll
                for (int ni = 0; ni < 2; ni++)
                    s[mi][ni] = __builtin_amdgcn_mfma_f32_16x16x32_bf16(kf[mi], qf[ni][ks], s[mi][ni], 0, 0, 0);
        }

        // exp (no max-subtract; scores bounded ~|2|), per-lane l accum, packed P store
        #pragma unroll
        for (int mi = 0; mi < 4; mi++) {
            #pragma unroll
            for (int ni = 0; ni < 2; ni++) {
                float p0 = __expf(s[mi][ni][0]);
                float p1 = __expf(s[mi][ni][1]);
                float p2 = __expf(s[mi][ni][2]);
                float p3 = __expf(s[mi][ni][3]);
                lsum[ni] += (p0 + p1) + (p2 + p3);
                ushort4 pk;
                pk.x = f2bf(p0); pk.y = f2bf(p1); pk.z = f2bf(p2); pk.w = f2bf(p3);
                *reinterpret_cast<ushort4*>(&PsW[ni * 16 + l16][mi * 16 + quad * 4]) = pk;
            }
        }

        // O += P @ V (P from wave-private LDS rows, V from swizzled LDS)
        #pragma unroll
        for (int ks = 0; ks < 2; ks++) {
            bf16x8 vf[4], pf[2];
            #pragma unroll
            for (int di = 0; di < 4; di++) {
                int row = di * 16 + l16;
                int ch = (ks * 4 + quad) ^ swz;
                vf[di] = *reinterpret_cast<const bf16x8*>(&Vs[buf][row * 64 + ch * 8]);
            }
            #pragma unroll
            for (int mi = 0; mi < 2; mi++)
                pf[mi] = *reinterpret_cast<const bf16x8*>(&PsW[mi * 16 + l16][ks * 32 + quad * 8]);
            #pragma unroll
            for (int mi = 0; mi < 2; mi++)
                #pragma unroll
                for (int di = 0; di < 4; di++)
                    o[mi][di] = __builtin_amdgcn_mfma_f32_16x16x32_bf16(pf[mi], vf[di], o[mi][di], 0, 0, 0);
        }

        __syncthreads();   // all waves done reading buf; next staging (buf^1) drained
        buf ^= 1;
    }

    // finalize l: reduce across quads (value for query ni*16+l16, replicated)
    #pragma unroll
    for (int ni = 0; ni < 2; ni++) {
        lsum[ni] += __shfl_xor(lsum[ni], 16, 64);
        lsum[ni] += __shfl_xor(lsum[ni], 32, 64);
    }

    // epilogue: O rows are queries (quad*4+r); fetch that row's l via shfl(width 16)
    #pragma unroll
    for (int mi = 0; mi < 2; mi++) {
        #pragma unroll
        for (int r = 0; r < 4; r++) {
            float lv = __shfl(lsum[mi], quad * 4 + r, 16);
            float inv = 1.0f / lv;
            int n = qt * 256 + wave * 32 + mi * 16 + quad * 4 + r;
            size_t base = (size_t)(b * 1024 + n) * 768 + h * 64;
            #pragma unroll
            for (int di = 0; di < 4; di++)
                ao[base + di * 16 + l16] = f2bf(o[mi][di][r] * inv);
        }
    }
}

// ---------------- output projection GEMM (v7: +XCD swizzle; +bias, fp32 out) ----------------
__global__ __launch_bounds__(512, 2) void gemm_proj(
    const u16* __restrict__ A, const u16* __restrict__ Bm,
    const float* __restrict__ bias, float* __restrict__ out)
{
    __shared__ u16 As[3][16384];
    __shared__ u16 Bs[3][8192];
    const int tid = threadIdx.x;
    const int wave = tid >> 6, lane = tid & 63;
    const int quad = lane >> 4, l16 = lane & 15;
    const int wm = wave >> 1, wn = wave & 1;
    // XCD-chunked swizzle: nwg=192, 8 XCDs x 24 = 4 full A-panels of 6 each.
    const int id = blockIdx.x + 6 * blockIdx.y;
    const int nid = (id & 7) * 24 + (id >> 3);
    const int bx = nid % 6, by = nid / 6;
    const int rowBase = by * 256;
    const int colBase = bx * 128;

    f32x4 acc[4][4] = {};
    kloop256(A + (size_t)rowBase * 768, Bm + (size_t)colBase * 768,
             &As[0][0], &Bs[0][0], acc, tid, wm, wn, quad, l16);

    #pragma unroll
    for (int mi = 0; mi < 4; mi++) {
        #pragma unroll
        for (int ni = 0; ni < 4; ni++) {
            int gj = colBase + wn * 64 + ni * 16 + l16;
            float bv = bias[gj];
            int gi0 = rowBase + wm * 64 + mi * 16 + quad * 4;
            #pragma unroll
            for (int rr2 = 0; rr2 < 4; rr2++)
                out[(size_t)(gi0 + rr2) * 768 + gj] = acc[mi][ni][rr2] + bv;
        }
    }
}

extern "C" void kernel_launch(void* const* d_in, const int* in_sizes, int n_in,
                              void* d_out, int out_size, void* d_ws, size_t ws_size,
                              hipStream_t stream) {
    const float* x  = (const float*)d_in[0];
    const float* Wq = (const float*)d_in[1];
    const float* Wk = (const float*)d_in[2];
    const float* Wv = (const float*)d_in[3];
    const float* Wp = (const float*)d_in[4];
    const float* bp = (const float*)d_in[5];
    float* out = (float*)d_out;

    // workspace layout (bf16 elements); total ~64.5 MB
    u16* xb  = (u16*)d_ws;            // 6291456  : x as bf16 [8192][768]
    u16* wb  = xb  + 6291456;         // 1769472  : Wq|Wk|Wv [2304][768]
    u16* wpb = wb  + 1769472;         // 589824   : Wp [768][768]
    u16* qo  = wpb + 589824;          // 6291456  : q [B,H,N,D] (scaled)
    u16* ko  = qo  + 6291456;         // 6291456  : k [B,H,N,D]
    u16* vto = ko  + 6291456;         // 6291456  : v^T [B,H,D,N]
    u16* ao  = vto + 6291456;         // 6291456  : attn out [B,N,H*D]

    cast_all<<<8448, 256, 0, stream>>>(x, Wq, Wk, Wv, Wp, xb, wb, wpb);
    gemm_qkv<<<dim3(18, 32), 512, 0, stream>>>(xb, wb, qo, ko, vto);
    attn_fwd<<<dim3(96, 4), 512, 0, stream>>>(qo, ko, vto, ao);
    gemm_proj<<<dim3(6, 32), 512, 0, stream>>>(ao, wpb, bp, out);
}

// Round 5
// 189.387 us; speedup vs baseline: 1.0334x; 1.0334x over previous
//
#include <hip/hip_runtime.h>

typedef unsigned short u16;
typedef __attribute__((ext_vector_type(8))) __bf16 bf16x8;
typedef __attribute__((ext_vector_type(4))) float f32x4;
typedef __attribute__((ext_vector_type(16))) float f32x16;

__device__ __forceinline__ u16 f2bf(float f) {
    union { float f; unsigned u; } v; v.f = f;
    unsigned u = v.u;
    u += 0x7FFFu + ((u >> 16) & 1u);
    return (u16)(u >> 16);
}

// pack two f32 -> u32 of 2x bf16 (RNE); compiler emits v_cvt_pk_bf16_f32 (m240)
__device__ __forceinline__ unsigned pk2(float lo, float hi) {
    union { __bf16 h[2]; unsigned u; } x;
    x.h[0] = (__bf16)lo; x.h[1] = (__bf16)hi;
    return x.u;
}
// exchange upper 32 lanes of a with lower 32 lanes of b (compiler-managed hazards)
__device__ __forceinline__ void pswap(unsigned &a, unsigned &b) {
    auto r = __builtin_amdgcn_permlane32_swap(a, b, false, false);
    a = r[0]; b = r[1];
}

// async global->LDS copy, 16B per lane (m97 pattern)
typedef const __attribute__((address_space(1))) void GV;
typedef __attribute__((address_space(3))) void LV;
__device__ __forceinline__ void gl2lds16(const void* g, void* l) {
    __builtin_amdgcn_global_load_lds((GV*)g, (LV*)l, 16, 0, 0);
}

// ---------------- fused cast fp32 -> bf16 (x + 4 weights in ONE launch) ----------------
__global__ __launch_bounds__(256) void cast_all(
    const float* __restrict__ x,  const float* __restrict__ Wq,
    const float* __restrict__ Wk, const float* __restrict__ Wv,
    const float* __restrict__ Wp,
    u16* __restrict__ xb, u16* __restrict__ wb, u16* __restrict__ wpb)
{
    int bid = blockIdx.x;
    const float4* s; ushort4* d; int idx;
    if (bid < 6144) {                    // x: 1572864 float4 = 6144 blocks
        s = (const float4*)x; d = (ushort4*)xb; idx = bid * 256 + threadIdx.x;
    } else {                             // weights: 147456 float4 = 576 blocks each
        int t = bid - 6144;
        int w = t / 576;
        idx = (t - w * 576) * 256 + threadIdx.x;
        s = (const float4*)(w == 0 ? Wq : w == 1 ? Wk : w == 2 ? Wv : Wp);
        d = (ushort4*)(w == 3 ? wpb : wb + w * 589824);
    }
    float4 f = s[idx];
    ushort4 o;
    o.x = f2bf(f.x); o.y = f2bf(f.y); o.z = f2bf(f.z); o.w = f2bf(f.w);
    d[idx] = o;
}

// ---------------- GEMM v7: BM=256/BN=128/BK=64, ring-3, 2-phase, XCD swizzle ----------------
__device__ __forceinline__ void stage_g(const u16* src, int k0, u16* lds, int g, int tid) {
    int i = g * 512 + tid;               // 16B chunk id
    int row = i >> 3, p = i & 7;
    int l = p ^ (row & 7);
    gl2lds16(src + (size_t)row * 768 + k0 + l * 8, lds + i * 8);
}
__device__ __forceinline__ const bf16x8* frag64(const u16* lds, int row, int kc) {
    return reinterpret_cast<const bf16x8*>(lds + row * 64 + ((kc ^ (row & 7)) * 8));
}

__device__ __forceinline__ void kloop256(
    const u16* __restrict__ aSrc, const u16* __restrict__ bSrc,
    u16* As, u16* Bs, f32x4 (&acc)[4][4],
    int tid, int wm, int wn, int quad, int l16)
{
    #pragma unroll
    for (int tt = 0; tt < 2; tt++) {
        #pragma unroll
        for (int g = 0; g < 4; g++) stage_g(aSrc, tt * 64, As + tt * 16384, g, tid);
        #pragma unroll
        for (int g = 0; g < 2; g++) stage_g(bSrc, tt * 64, Bs + tt * 8192, g, tid);
    }
    asm volatile("s_waitcnt vmcnt(6)" ::: "memory");
    __builtin_amdgcn_s_barrier();
    asm volatile("" ::: "memory");

    int buf = 0;
    for (int t = 0; t < 12; t++) {
        const u16* Ab = As + buf * 16384;
        const u16* Bb = Bs + buf * 8192;
        int sb = buf + 2; if (sb >= 3) sb -= 3;
        u16* Asb = As + sb * 16384;
        u16* Bsb = Bs + sb * 8192;
        const bool pf = (t + 2 < 12);
        const int k2 = (t + 2) * 64;

        // ---- phase A (k-half 0) ----
        bf16x8 a[4], b[4];
        #pragma unroll
        for (int mi = 0; mi < 4; mi++) a[mi] = *frag64(Ab, wm * 64 + mi * 16 + l16, quad);
        #pragma unroll
        for (int ni = 0; ni < 4; ni++) b[ni] = *frag64(Bb, wn * 64 + ni * 16 + l16, quad);
        if (pf) {
            stage_g(aSrc, k2, Asb, 0, tid);
            stage_g(aSrc, k2, Asb, 1, tid);
            stage_g(aSrc, k2, Asb, 2, tid);
        }
        __builtin_amdgcn_s_barrier();
        asm volatile("" ::: "memory");
        __builtin_amdgcn_s_setprio(1);
        #pragma unroll
        for (int mi = 0; mi < 4; mi++)
            #pragma unroll
            for (int ni = 0; ni < 4; ni++)
                acc[mi][ni] = __builtin_amdgcn_mfma_f32_16x16x32_bf16(a[mi], b[ni], acc[mi][ni], 0, 0, 0);
        __builtin_amdgcn_s_setprio(0);

        // ---- phase B (k-half 1) ----
        #pragma unroll
        for (int mi = 0; mi < 4; mi++) a[mi] = *frag64(Ab, wm * 64 + mi * 16 + l16, 4 + quad);
        #pragma unroll
        for (int ni = 0; ni < 4; ni++) b[ni] = *frag64(Bb, wn * 64 + ni * 16 + l16, 4 + quad);
        if (pf) {
            stage_g(aSrc, k2, Asb, 3, tid);
            stage_g(bSrc, k2, Bsb, 0, tid);
            stage_g(bSrc, k2, Bsb, 1, tid);
        }
        if (t <= 9)       asm volatile("s_waitcnt vmcnt(6)" ::: "memory");
        else if (t == 10) asm volatile("s_waitcnt vmcnt(0)" ::: "memory");
        __builtin_amdgcn_s_barrier();
        asm volatile("" ::: "memory");
        __builtin_amdgcn_s_setprio(1);
        #pragma unroll
        for (int mi = 0; mi < 4; mi++)
            #pragma unroll
            for (int ni = 0; ni < 4; ni++)
                acc[mi][ni] = __builtin_amdgcn_mfma_f32_16x16x32_bf16(a[mi], b[ni], acc[mi][ni], 0, 0, 0);
        __builtin_amdgcn_s_setprio(0);

        buf++; if (buf == 3) buf = 0;
    }
}

// ---------------- QKV projection GEMM (v7; q scaled by 0.125 exact) ----------------
__global__ __launch_bounds__(512, 2) void gemm_qkv(
    const u16* __restrict__ A, const u16* __restrict__ Bm,
    u16* __restrict__ qo, u16* __restrict__ ko, u16* __restrict__ vto)
{
    __shared__ u16 As[3][16384];         // 96 KB
    __shared__ u16 Bs[3][8192];          // 48 KB
    const int tid = threadIdx.x;
    const int wave = tid >> 6, lane = tid & 63;
    const int quad = lane >> 4, l16 = lane & 15;
    const int wm = wave >> 1, wn = wave & 1;      // 4M x 2N waves
    // XCD-chunked swizzle (T1): 576 blocks = 8 XCDs x 72 (bijective, 576%8==0)
    const int id = blockIdx.x + 18 * blockIdx.y;
    const int nid = (id & 7) * 72 + (id >> 3);
    const int bx = nid % 18, by = nid / 18;
    const int rowBase = by * 256;
    const int colBase = bx * 128;

    f32x4 acc[4][4] = {};
    kloop256(A + (size_t)rowBase * 768, Bm + (size_t)colBase * 768,
             &As[0][0], &Bs[0][0], acc, tid, wm, wn, quad, l16);

    #pragma unroll
    for (int mi = 0; mi < 4; mi++) {
        #pragma unroll
        for (int ni = 0; ni < 4; ni++) {
            int gj = colBase + wn * 64 + ni * 16 + l16;   // 0..2303
            int which = gj / 768;                         // 0=q,1=k,2=v (uniform per tile)
            int r = gj - which * 768;
            int h = r >> 6, d = r & 63;
            int gi0 = rowBase + wm * 64 + mi * 16 + quad * 4;
            int b_ = gi0 >> 10;                           // constant across 4 rows (gi0 % 4 == 0)
            int n0 = gi0 & 1023;
            if (which == 2) {
                ushort4 pk;
                pk.x = f2bf(acc[mi][ni][0]);
                pk.y = f2bf(acc[mi][ni][1]);
                pk.z = f2bf(acc[mi][ni][2]);
                pk.w = f2bf(acc[mi][ni][3]);
                *reinterpret_cast<ushort4*>(vto + ((size_t)(b_ * 12 + h) * 64 + d) * 1024 + n0) = pk;
            } else {
                float s = (which == 0) ? 0.125f : 1.0f;
                u16* dst = (which == 0 ? qo : ko) + ((size_t)(b_ * 12 + h) * 1024 + n0) * 64 + d;
                #pragma unroll
                for (int rr = 0; rr < 4; rr++)
                    dst[(size_t)rr * 64] = f2bf(acc[mi][ni][rr] * s);
            }
        }
    }
}

// ---------------- fused flash attention (v9.1: 32x32 MFMA, in-register P; builtin ops) ----------------
// q,k: [B,H,N,D] bf16 (q pre-scaled by 0.125), vt: [B,H,D,N] bf16, ao: [B,N,H*D] bf16
// 4 waves x 32 queries = 128 q/block; grid 96 x 8 = 768 blocks @ 3/CU.
// S^T = mfma32x32(K, Q): lane holds 32 keys for query lane&31. P built IN REGISTERS:
// bf16-cast pairs (compiler cvt_pk) + __builtin_amdgcn_permlane32_swap (documented:
// first.hi <-> second.lo; hazards handled by compiler). No P LDS round-trip.
__global__ __launch_bounds__(256, 3) void attn_fwd(
    const u16* __restrict__ q, const u16* __restrict__ k,
    const u16* __restrict__ vt, u16* __restrict__ ao)
{
    __shared__ u16 Ks[2][4096];      // [key 0..63][d-chunk phys 0..7][8 bf16]
    __shared__ u16 Vs[2][4096];      // [d 0..63][key-chunk phys 0..7][8 bf16]
    const int bh = blockIdx.x, qt = blockIdx.y;   // bh fast => same head -> same XCD
    const int b = bh / 12, h = bh - b * 12;
    const int tid = threadIdx.x;
    const int wave = tid >> 6, lane = tid & 63;
    const int l31 = lane & 31, hi = lane >> 5;
    const int sw = l31 & 7;

    const u16* qb = q + (size_t)bh * 65536 + ((size_t)qt * 128 + wave * 32) * 64;
    const u16* kb = k + (size_t)bh * 65536;
    const u16* vb = vt + (size_t)bh * 65536;

    auto stage = [&](int buf, int j0) {
        #pragma unroll
        for (int r = 0; r < 2; r++) {
            int i = r * 256 + tid;               // 0..511, 16B each
            int row = i >> 3, cp = i & 7;
            int cl = cp ^ (row & 7);
            gl2lds16((const char*)kb + (size_t)(j0 + row) * 128 + cl * 16,
                     (char*)&Ks[buf][0] + i * 16);
        }
        #pragma unroll
        for (int r = 0; r < 2; r++) {
            int i = r * 256 + tid;
            int row = i >> 3, cp = i & 7;
            int cl = cp ^ (row & 7);
            gl2lds16((const char*)vb + (size_t)row * 2048 + (size_t)j0 * 2 + cl * 16,
                     (char*)&Vs[buf][0] + i * 16);
        }
    };

    stage(0, 0);

    // Q B-frags: B[k = dk*16 + hi*8 + j][n = query l31]
    bf16x8 qf[4];
    #pragma unroll
    for (int dk = 0; dk < 4; dk++)
        qf[dk] = *reinterpret_cast<const bf16x8*>(qb + l31 * 64 + dk * 16 + hi * 8);

    f32x16 o0 = {}, o1 = {};         // O[query 32][d 0-31 / 32-63]
    float lsum = 0.f;                // partial row-sum for query l31

    __syncthreads();                 // chunk 0 staged (vmcnt(0) at barrier)

    int buf = 0;
    for (int j0 = 0; j0 < 1024; j0 += 64) {
        if (j0 + 64 < 1024) stage(buf ^ 1, j0 + 64);   // async prefetch next chunk

        // S^T[key][query]: A = K (keys 0-31 / 32-63), B = Q
        f32x16 s0 = {}, s1 = {};
        #pragma unroll
        for (int dk = 0; dk < 4; dk++) {
            int ch = ((2 * dk + hi) ^ sw) * 8;
            bf16x8 kf0 = *reinterpret_cast<const bf16x8*>(&Ks[buf][l31 * 64 + ch]);
            bf16x8 kf1 = *reinterpret_cast<const bf16x8*>(&Ks[buf][(32 + l31) * 64 + ch]);
            s0 = __builtin_amdgcn_mfma_f32_32x32x16_bf16(kf0, qf[dk], s0, 0, 0, 0);
            s1 = __builtin_amdgcn_mfma_f32_32x32x16_bf16(kf1, qf[dk], s1, 0, 0, 0);
        }

        // exp (scores bounded ~|2|; v7-identical numerics), in-register pack to PV A-frags.
        // S row = (reg&3) + 8*(reg>>2) + 4*hi. Frag word pairing (W_i, W_{i+2}) +
        // permlane32_swap fills both output words (T12 recipe, element-trace verified).
        bf16x8 pa[4];
        #pragma unroll
        for (int kbk = 0; kbk < 2; kbk++) {
            float p[16];
            #pragma unroll
            for (int r = 0; r < 16; r++) {
                p[r] = __expf(kbk ? s1[r] : s0[r]);
                lsum += p[r];
            }
            unsigned W00 = pk2(p[0],  p[1]),  W01 = pk2(p[2],  p[3]);
            unsigned W10 = pk2(p[4],  p[5]),  W11 = pk2(p[6],  p[7]);
            unsigned W20 = pk2(p[8],  p[9]),  W21 = pk2(p[10], p[11]);
            unsigned W30 = pk2(p[12], p[13]), W31 = pk2(p[14], p[15]);
            pswap(W00, W10); pswap(W01, W11);   // kslice 2*kbk+0
            pswap(W20, W30); pswap(W21, W31);   // kslice 2*kbk+1
            union { unsigned u[4]; bf16x8 v; } pk0, pk1;
            pk0.u[0] = W00; pk0.u[1] = W01; pk0.u[2] = W10; pk0.u[3] = W11;
            pk1.u[0] = W20; pk1.u[1] = W21; pk1.u[2] = W30; pk1.u[3] = W31;
            pa[kbk * 2 + 0] = pk0.v;
            pa[kbk * 2 + 1] = pk1.v;
        }

        // O += P @ V: B = V[key][d], d-col = l31 (+32), key = ks*16 + hi*8 + j
        #pragma unroll
        for (int ks = 0; ks < 4; ks++) {
            int ch = ((2 * ks + hi) ^ sw) * 8;
            bf16x8 vf0 = *reinterpret_cast<const bf16x8*>(&Vs[buf][l31 * 64 + ch]);
            bf16x8 vf1 = *reinterpret_cast<const bf16x8*>(&Vs[buf][(32 + l31) * 64 + ch]);
            o0 = __builtin_amdgcn_mfma_f32_32x32x16_bf16(pa[ks], vf0, o0, 0, 0, 0);
            o1 = __builtin_amdgcn_mfma_f32_32x32x16_bf16(pa[ks], vf1, o1, 0, 0, 0);
        }

        __syncthreads();   // all waves done reading buf; next staging drained
        buf ^= 1;
    }

    // lane + partner(l^32) hold complementary keys for the SAME query l31
    lsum += __shfl_xor(lsum, 32, 64);

    // epilogue: O rows are queries (reg&3)+8*(reg>>2)+4*hi; cols are d = l31 (+32)
    #pragma unroll
    for (int r = 0; r < 16; r++) {
        int qrow = (r & 3) + 8 * (r >> 2) + 4 * hi;
        float lv = __shfl(lsum, qrow, 32);
        float inv = 1.0f / lv;
        int n = qt * 128 + wave * 32 + qrow;
        size_t base = (size_t)(b * 1024 + n) * 768 + h * 64;
        ao[base + l31]      = f2bf(o0[r] * inv);
        ao[base + 32 + l31] = f2bf(o1[r] * inv);
    }
}

// ---------------- output projection GEMM (v7: +XCD swizzle; +bias, fp32 out) ----------------
__global__ __launch_bounds__(512, 2) void gemm_proj(
    const u16* __restrict__ A, const u16* __restrict__ Bm,
    const float* __restrict__ bias, float* __restrict__ out)
{
    __shared__ u16 As[3][16384];
    __shared__ u16 Bs[3][8192];
    const int tid = threadIdx.x;
    const int wave = tid >> 6, lane = tid & 63;
    const int quad = lane >> 4, l16 = lane & 15;
    const int wm = wave >> 1, wn = wave & 1;
    // XCD-chunked swizzle: 192 blocks = 8 XCDs x 24
    const int id = blockIdx.x + 6 * blockIdx.y;
    const int nid = (id & 7) * 24 + (id >> 3);
    const int bx = nid % 6, by = nid / 6;
    const int rowBase = by * 256;
    const int colBase = bx * 128;

    f32x4 acc[4][4] = {};
    kloop256(A + (size_t)rowBase * 768, Bm + (size_t)colBase * 768,
             &As[0][0], &Bs[0][0], acc, tid, wm, wn, quad, l16);

    #pragma unroll
    for (int mi = 0; mi < 4; mi++) {
        #pragma unroll
        for (int ni = 0; ni < 4; ni++) {
            int gj = colBase + wn * 64 + ni * 16 + l16;
            float bv = bias[gj];
            int gi0 = rowBase + wm * 64 + mi * 16 + quad * 4;
            #pragma unroll
            for (int rr2 = 0; rr2 < 4; rr2++)
                out[(size_t)(gi0 + rr2) * 768 + gj] = acc[mi][ni][rr2] + bv;
        }
    }
}

extern "C" void kernel_launch(void* const* d_in, const int* in_sizes, int n_in,
                              void* d_out, int out_size, void* d_ws, size_t ws_size,
                              hipStream_t stream) {
    const float* x  = (const float*)d_in[0];
    const float* Wq = (const float*)d_in[1];
    const float* Wk = (const float*)d_in[2];
    const float* Wv = (const float*)d_in[3];
    const float* Wp = (const float*)d_in[4];
    const float* bp = (const float*)d_in[5];
    float* out = (float*)d_out;

    // workspace layout (bf16 elements); total ~64.5 MB
    u16* xb  = (u16*)d_ws;            // 6291456  : x as bf16 [8192][768]
    u16* wb  = xb  + 6291456;         // 1769472  : Wq|Wk|Wv [2304][768]
    u16* wpb = wb  + 1769472;         // 589824   : Wp [768][768]
    u16* qo  = wpb + 589824;          // 6291456  : q [B,H,N,D] (scaled by 0.125)
    u16* ko  = qo  + 6291456;         // 6291456  : k [B,H,N,D]
    u16* vto = ko  + 6291456;         // 6291456  : v^T [B,H,D,N]
    u16* ao  = vto + 6291456;         // 6291456  : attn out [B,N,H*D]

    cast_all<<<8448, 256, 0, stream>>>(x, Wq, Wk, Wv, Wp, xb, wb, wpb);
    gemm_qkv<<<dim3(18, 32), 512, 0, stream>>>(xb, wb, qo, ko, vto);
    attn_fwd<<<dim3(96, 8), 256, 0, stream>>>(qo, ko, vto, ao);
    gemm_proj<<<dim3(6, 32), 512, 0, stream>>>(ao, wpb, bp, out);
}

// Round 6
// 187.292 us; speedup vs baseline: 1.0449x; 1.0112x over previous
//
#include <hip/hip_runtime.h>

typedef unsigned short u16;
typedef __attribute__((ext_vector_type(8))) __bf16 bf16x8;
typedef __attribute__((ext_vector_type(4))) float f32x4;
typedef __attribute__((ext_vector_type(16))) float f32x16;

__device__ __forceinline__ u16 f2bf(float f) {
    union { float f; unsigned u; } v; v.f = f;
    unsigned u = v.u;
    u += 0x7FFFu + ((u >> 16) & 1u);
    return (u16)(u >> 16);
}

// pack two f32 -> u32 of 2x bf16 (RNE); compiler emits v_cvt_pk_bf16_f32 (m240)
__device__ __forceinline__ unsigned pk2(float lo, float hi) {
    union { __bf16 h[2]; unsigned u; } x;
    x.h[0] = (__bf16)lo; x.h[1] = (__bf16)hi;
    return x.u;
}
// exchange upper 32 lanes of a with lower 32 lanes of b (compiler-managed hazards)
__device__ __forceinline__ void pswap(unsigned &a, unsigned &b) {
    auto r = __builtin_amdgcn_permlane32_swap(a, b, false, false);
    a = r[0]; b = r[1];
}

// async global->LDS copy, 16B per lane (m97 pattern)
typedef const __attribute__((address_space(1))) void GV;
typedef __attribute__((address_space(3))) void LV;
__device__ __forceinline__ void gl2lds16(const void* g, void* l) {
    __builtin_amdgcn_global_load_lds((GV*)g, (LV*)l, 16, 0, 0);
}

// ---------------- fused cast fp32 -> bf16 (x + 4 weights in ONE launch) ----------------
__global__ __launch_bounds__(256) void cast_all(
    const float* __restrict__ x,  const float* __restrict__ Wq,
    const float* __restrict__ Wk, const float* __restrict__ Wv,
    const float* __restrict__ Wp,
    u16* __restrict__ xb, u16* __restrict__ wb, u16* __restrict__ wpb)
{
    int bid = blockIdx.x;
    const float4* s; ushort4* d; int idx;
    if (bid < 6144) {                    // x: 1572864 float4 = 6144 blocks
        s = (const float4*)x; d = (ushort4*)xb; idx = bid * 256 + threadIdx.x;
    } else {                             // weights: 147456 float4 = 576 blocks each
        int t = bid - 6144;
        int w = t / 576;
        idx = (t - w * 576) * 256 + threadIdx.x;
        s = (const float4*)(w == 0 ? Wq : w == 1 ? Wk : w == 2 ? Wv : Wp);
        d = (ushort4*)(w == 3 ? wpb : wb + w * 589824);
    }
    float4 f = s[idx];
    ushort4 o;
    o.x = f2bf(f.x); o.y = f2bf(f.y); o.z = f2bf(f.z); o.w = f2bf(f.w);
    d[idx] = o;
}

// ---------------- GEMM v8: BK=32 ring-3, 2 blocks/CU, counted vmcnt, XCD swizzle ----------------
// Tile rows are 32 bf16 = 64 B; LDS stores 2-row LINES of 128 B / 8 chunks.
// Lane-linear LDS dest (global_load_lds constraint): phys chunk `pos` of line
// holds LOGICAL chunk pos ^ (line&7). Frag column read (16 consecutive rows,
// fixed k-chunk) -> 8 lines x 8 distinct positions, 2-way bank alias = free
// (round-1 verified SQ_LDS_BANK_CONFLICT=0 with this exact formula).
__device__ __forceinline__ void stage_c(const u16* src, int k0, u16* lds, int i) {
    int line = i >> 3, pos = i & 7;
    int p = pos ^ (line & 7);                 // logical chunk in this phys slot
    int r = line * 2 + (p >> 2), c = p & 3;
    gl2lds16(src + (size_t)r * 768 + k0 + c * 8, lds + i * 8);
}
__device__ __forceinline__ const bf16x8* fragK(const u16* lds, int row, int quad) {
    int line = row >> 1;
    int pos = (((row & 1) << 2) | quad) ^ (line & 7);
    return reinterpret_cast<const bf16x8*>(lds + line * 64 + pos * 8);
}

// ---------------- QKV projection GEMM (v8: BM=256/BN=128/BK=32, 72 KB LDS) ----------------
// A = xb [8192][768] bf16, Bm = wb [2304][768] bf16 (Wq|Wk|Wv rows, K-contig)
// out: q,k as [B,H,N,D] bf16 (q scaled 0.125), v transposed as [B,H,D,N] bf16
// 24 K-tiles, ring-3, prefetch dist 2, 3 loads/thread/tile -> boundary vmcnt(3)
// (never 0 mid-loop, T4). 2 blocks/CU restores cross-block latency hiding (m103).
__global__ __launch_bounds__(512, 4) void gemm_qkv(
    const u16* __restrict__ A, const u16* __restrict__ Bm,
    u16* __restrict__ qo, u16* __restrict__ ko, u16* __restrict__ vto)
{
    __shared__ u16 As[3][8192];          // 3 x 16 KB
    __shared__ u16 Bs[3][4096];          // 3 x  8 KB   (72 KB total -> 2 blocks/CU)
    const int tid = threadIdx.x;
    const int wave = tid >> 6, lane = tid & 63;
    const int quad = lane >> 4, l16 = lane & 15;
    const int wm = wave >> 1, wn = wave & 1;      // 4M x 2N waves, per-wave 64x64
    // XCD-chunked swizzle (T1): 576 blocks = 8 XCDs x 72 (bijective, 576%8==0)
    const int id = blockIdx.x + 18 * blockIdx.y;
    const int nid = (id & 7) * 72 + (id >> 3);
    const int bx = nid % 18, by = nid / 18;
    const int rowBase = by * 256;
    const int colBase = bx * 128;

    const u16* aSrc = A + (size_t)rowBase * 768;
    const u16* bSrc = Bm + (size_t)colBase * 768;
    f32x4 acc[4][4] = {};

    // prologue: stage tiles 0,1 (A: 1024 chunks = 2/thread, B: 512 = 1/thread)
    #pragma unroll
    for (int tt = 0; tt < 2; tt++) {
        stage_c(aSrc, tt * 32, As[tt], tid);
        stage_c(aSrc, tt * 32, As[tt], 512 + tid);
        stage_c(bSrc, tt * 32, Bs[tt], tid);
    }
    asm volatile("s_waitcnt vmcnt(3)" ::: "memory");   // tile 0 landed, tile 1 in flight
    __builtin_amdgcn_s_barrier();
    asm volatile("" ::: "memory");

    int buf = 0;
    for (int t = 0; t < 24; t++) {
        bf16x8 a[4], b[4];
        #pragma unroll
        for (int mi = 0; mi < 4; mi++) a[mi] = *fragK(As[buf], wm * 64 + mi * 16 + l16, quad);
        #pragma unroll
        for (int ni = 0; ni < 4; ni++) b[ni] = *fragK(Bs[buf], wn * 64 + ni * 16 + l16, quad);
        int sb = buf + 2; if (sb >= 3) sb -= 3;
        if (t + 2 < 24) {                // stage tile t+2 into buf of t-1 (all waves
            int k2 = (t + 2) * 32;       // passed the barrier after reading it)
            stage_c(aSrc, k2, As[sb], tid);
            stage_c(aSrc, k2, As[sb], 512 + tid);
            stage_c(bSrc, k2, Bs[sb], tid);
        }
        // boundary wait: retire tile t+1's 3 loads, keep t+2's 3 in flight
        if (t <= 21)      asm volatile("s_waitcnt vmcnt(3)" ::: "memory");
        else if (t == 22) asm volatile("s_waitcnt vmcnt(0)" ::: "memory");
        __builtin_amdgcn_s_barrier();
        asm volatile("" ::: "memory");
        __builtin_amdgcn_s_setprio(1);
        #pragma unroll
        for (int mi = 0; mi < 4; mi++)
            #pragma unroll
            for (int ni = 0; ni < 4; ni++)
                acc[mi][ni] = __builtin_amdgcn_mfma_f32_16x16x32_bf16(a[mi], b[ni], acc[mi][ni], 0, 0, 0);
        __builtin_amdgcn_s_setprio(0);
        buf = (buf == 2) ? 0 : buf + 1;
    }

    #pragma unroll
    for (int mi = 0; mi < 4; mi++) {
        #pragma unroll
        for (int ni = 0; ni < 4; ni++) {
            int gj = colBase + wn * 64 + ni * 16 + l16;   // 0..2303
            int which = gj / 768;                         // 0=q,1=k,2=v (uniform per tile)
            int r = gj - which * 768;
            int h = r >> 6, d = r & 63;
            int gi0 = rowBase + wm * 64 + mi * 16 + quad * 4;
            int b_ = gi0 >> 10;                           // constant across 4 rows
            int n0 = gi0 & 1023;
            if (which == 2) {
                ushort4 pk;
                pk.x = f2bf(acc[mi][ni][0]);
                pk.y = f2bf(acc[mi][ni][1]);
                pk.z = f2bf(acc[mi][ni][2]);
                pk.w = f2bf(acc[mi][ni][3]);
                *reinterpret_cast<ushort4*>(vto + ((size_t)(b_ * 12 + h) * 64 + d) * 1024 + n0) = pk;
            } else {
                float s = (which == 0) ? 0.125f : 1.0f;
                u16* dst = (which == 0 ? qo : ko) + ((size_t)(b_ * 12 + h) * 1024 + n0) * 64 + d;
                #pragma unroll
                for (int rr = 0; rr < 4; rr++)
                    dst[(size_t)rr * 64] = f2bf(acc[mi][ni][rr] * s);
            }
        }
    }
}

// ---------------- fused flash attention (v9.1, unchanged) ----------------
__global__ __launch_bounds__(256, 3) void attn_fwd(
    const u16* __restrict__ q, const u16* __restrict__ k,
    const u16* __restrict__ vt, u16* __restrict__ ao)
{
    __shared__ u16 Ks[2][4096];      // [key 0..63][d-chunk phys 0..7][8 bf16]
    __shared__ u16 Vs[2][4096];      // [d 0..63][key-chunk phys 0..7][8 bf16]
    const int bh = blockIdx.x, qt = blockIdx.y;   // bh fast => same head -> same XCD
    const int b = bh / 12, h = bh - b * 12;
    const int tid = threadIdx.x;
    const int wave = tid >> 6, lane = tid & 63;
    const int l31 = lane & 31, hi = lane >> 5;
    const int sw = l31 & 7;

    const u16* qb = q + (size_t)bh * 65536 + ((size_t)qt * 128 + wave * 32) * 64;
    const u16* kb = k + (size_t)bh * 65536;
    const u16* vb = vt + (size_t)bh * 65536;

    auto stage = [&](int buf, int j0) {
        #pragma unroll
        for (int r = 0; r < 2; r++) {
            int i = r * 256 + tid;               // 0..511, 16B each
            int row = i >> 3, cp = i & 7;
            int cl = cp ^ (row & 7);
            gl2lds16((const char*)kb + (size_t)(j0 + row) * 128 + cl * 16,
                     (char*)&Ks[buf][0] + i * 16);
        }
        #pragma unroll
        for (int r = 0; r < 2; r++) {
            int i = r * 256 + tid;
            int row = i >> 3, cp = i & 7;
            int cl = cp ^ (row & 7);
            gl2lds16((const char*)vb + (size_t)row * 2048 + (size_t)j0 * 2 + cl * 16,
                     (char*)&Vs[buf][0] + i * 16);
        }
    };

    stage(0, 0);

    bf16x8 qf[4];
    #pragma unroll
    for (int dk = 0; dk < 4; dk++)
        qf[dk] = *reinterpret_cast<const bf16x8*>(qb + l31 * 64 + dk * 16 + hi * 8);

    f32x16 o0 = {}, o1 = {};         // O[query 32][d 0-31 / 32-63]
    float lsum = 0.f;                // partial row-sum for query l31

    __syncthreads();

    int buf = 0;
    for (int j0 = 0; j0 < 1024; j0 += 64) {
        if (j0 + 64 < 1024) stage(buf ^ 1, j0 + 64);

        f32x16 s0 = {}, s1 = {};
        #pragma unroll
        for (int dk = 0; dk < 4; dk++) {
            int ch = ((2 * dk + hi) ^ sw) * 8;
            bf16x8 kf0 = *reinterpret_cast<const bf16x8*>(&Ks[buf][l31 * 64 + ch]);
            bf16x8 kf1 = *reinterpret_cast<const bf16x8*>(&Ks[buf][(32 + l31) * 64 + ch]);
            s0 = __builtin_amdgcn_mfma_f32_32x32x16_bf16(kf0, qf[dk], s0, 0, 0, 0);
            s1 = __builtin_amdgcn_mfma_f32_32x32x16_bf16(kf1, qf[dk], s1, 0, 0, 0);
        }

        bf16x8 pa[4];
        #pragma unroll
        for (int kbk = 0; kbk < 2; kbk++) {
            float p[16];
            #pragma unroll
            for (int r = 0; r < 16; r++) {
                p[r] = __expf(kbk ? s1[r] : s0[r]);
                lsum += p[r];
            }
            unsigned W00 = pk2(p[0],  p[1]),  W01 = pk2(p[2],  p[3]);
            unsigned W10 = pk2(p[4],  p[5]),  W11 = pk2(p[6],  p[7]);
            unsigned W20 = pk2(p[8],  p[9]),  W21 = pk2(p[10], p[11]);
            unsigned W30 = pk2(p[12], p[13]), W31 = pk2(p[14], p[15]);
            pswap(W00, W10); pswap(W01, W11);
            pswap(W20, W30); pswap(W21, W31);
            union { unsigned u[4]; bf16x8 v; } pk0, pk1;
            pk0.u[0] = W00; pk0.u[1] = W01; pk0.u[2] = W10; pk0.u[3] = W11;
            pk1.u[0] = W20; pk1.u[1] = W21; pk1.u[2] = W30; pk1.u[3] = W31;
            pa[kbk * 2 + 0] = pk0.v;
            pa[kbk * 2 + 1] = pk1.v;
        }

        #pragma unroll
        for (int ks = 0; ks < 4; ks++) {
            int ch = ((2 * ks + hi) ^ sw) * 8;
            bf16x8 vf0 = *reinterpret_cast<const bf16x8*>(&Vs[buf][l31 * 64 + ch]);
            bf16x8 vf1 = *reinterpret_cast<const bf16x8*>(&Vs[buf][(32 + l31) * 64 + ch]);
            o0 = __builtin_amdgcn_mfma_f32_32x32x16_bf16(pa[ks], vf0, o0, 0, 0, 0);
            o1 = __builtin_amdgcn_mfma_f32_32x32x16_bf16(pa[ks], vf1, o1, 0, 0, 0);
        }

        __syncthreads();
        buf ^= 1;
    }

    lsum += __shfl_xor(lsum, 32, 64);

    #pragma unroll
    for (int r = 0; r < 16; r++) {
        int qrow = (r & 3) + 8 * (r >> 2) + 4 * hi;
        float lv = __shfl(lsum, qrow, 32);
        float inv = 1.0f / lv;
        int n = qt * 128 + wave * 32 + qrow;
        size_t base = (size_t)(b * 1024 + n) * 768 + h * 64;
        ao[base + l31]      = f2bf(o0[r] * inv);
        ao[base + 32 + l31] = f2bf(o1[r] * inv);
    }
}

// ---------------- output projection GEMM (v8: BM=128/BN=128/BK=32, 48 KB, 3 blk/CU) ----------------
__global__ __launch_bounds__(256, 3) void gemm_proj(
    const u16* __restrict__ A, const u16* __restrict__ Bm,
    const float* __restrict__ bias, float* __restrict__ out)
{
    __shared__ u16 As[3][4096];          // 3 x 8 KB
    __shared__ u16 Bs[3][4096];          // 48 KB total -> 3 blocks/CU
    const int tid = threadIdx.x;
    const int wave = tid >> 6, lane = tid & 63;
    const int quad = lane >> 4, l16 = lane & 15;
    const int wr = (wave >> 1) * 64, wc = (wave & 1) * 64;   // 2M x 2N waves
    // XCD-chunked swizzle: 384 blocks = 8 XCDs x 48 (bijective, 384%8==0)
    const int id = blockIdx.x + 6 * blockIdx.y;
    const int nid = (id & 7) * 48 + (id >> 3);
    const int bx = nid % 6, by = nid / 6;
    const int rowBase = by * 128;
    const int colBase = bx * 128;

    const u16* aSrc = A + (size_t)rowBase * 768;
    const u16* bSrc = Bm + (size_t)colBase * 768;
    f32x4 acc[4][4] = {};

    // prologue: tiles 0,1 (A: 512 chunks = 2/thread, B same) -> 8 loads/thread
    #pragma unroll
    for (int tt = 0; tt < 2; tt++) {
        stage_c(aSrc, tt * 32, As[tt], tid);
        stage_c(aSrc, tt * 32, As[tt], 256 + tid);
        stage_c(bSrc, tt * 32, Bs[tt], tid);
        stage_c(bSrc, tt * 32, Bs[tt], 256 + tid);
    }
    asm volatile("s_waitcnt vmcnt(4)" ::: "memory");
    __builtin_amdgcn_s_barrier();
    asm volatile("" ::: "memory");

    int buf = 0;
    for (int t = 0; t < 24; t++) {
        bf16x8 a[4], b[4];
        #pragma unroll
        for (int mi = 0; mi < 4; mi++) a[mi] = *fragK(As[buf], wr + mi * 16 + l16, quad);
        #pragma unroll
        for (int ni = 0; ni < 4; ni++) b[ni] = *fragK(Bs[buf], wc + ni * 16 + l16, quad);
        int sb = buf + 2; if (sb >= 3) sb -= 3;
        if (t + 2 < 24) {
            int k2 = (t + 2) * 32;
            stage_c(aSrc, k2, As[sb], tid);
            stage_c(aSrc, k2, As[sb], 256 + tid);
            stage_c(bSrc, k2, Bs[sb], tid);
            stage_c(bSrc, k2, Bs[sb], 256 + tid);
        }
        if (t <= 21)      asm volatile("s_waitcnt vmcnt(4)" ::: "memory");
        else if (t == 22) asm volatile("s_waitcnt vmcnt(0)" ::: "memory");
        __builtin_amdgcn_s_barrier();
        asm volatile("" ::: "memory");
        __builtin_amdgcn_s_setprio(1);
        #pragma unroll
        for (int mi = 0; mi < 4; mi++)
            #pragma unroll
            for (int ni = 0; ni < 4; ni++)
                acc[mi][ni] = __builtin_amdgcn_mfma_f32_16x16x32_bf16(a[mi], b[ni], acc[mi][ni], 0, 0, 0);
        __builtin_amdgcn_s_setprio(0);
        buf = (buf == 2) ? 0 : buf + 1;
    }

    #pragma unroll
    for (int mi = 0; mi < 4; mi++) {
        #pragma unroll
        for (int ni = 0; ni < 4; ni++) {
            int gj = colBase + wc + ni * 16 + l16;
            float bv = bias[gj];
            int gi0 = rowBase + wr + mi * 16 + quad * 4;
            #pragma unroll
            for (int rr2 = 0; rr2 < 4; rr2++)
                out[(size_t)(gi0 + rr2) * 768 + gj] = acc[mi][ni][rr2] + bv;
        }
    }
}

extern "C" void kernel_launch(void* const* d_in, const int* in_sizes, int n_in,
                              void* d_out, int out_size, void* d_ws, size_t ws_size,
                              hipStream_t stream) {
    const float* x  = (const float*)d_in[0];
    const float* Wq = (const float*)d_in[1];
    const float* Wk = (const float*)d_in[2];
    const float* Wv = (const float*)d_in[3];
    const float* Wp = (const float*)d_in[4];
    const float* bp = (const float*)d_in[5];
    float* out = (float*)d_out;

    // workspace layout (bf16 elements); total ~64.5 MB
    u16* xb  = (u16*)d_ws;            // 6291456  : x as bf16 [8192][768]
    u16* wb  = xb  + 6291456;         // 1769472  : Wq|Wk|Wv [2304][768]
    u16* wpb = wb  + 1769472;         // 589824   : Wp [768][768]
    u16* qo  = wpb + 589824;          // 6291456  : q [B,H,N,D] (scaled by 0.125)
    u16* ko  = qo  + 6291456;         // 6291456  : k [B,H,N,D]
    u16* vto = ko  + 6291456;         // 6291456  : v^T [B,H,D,N]
    u16* ao  = vto + 6291456;         // 6291456  : attn out [B,N,H*D]

    cast_all<<<8448, 256, 0, stream>>>(x, Wq, Wk, Wv, Wp, xb, wb, wpb);
    gemm_qkv<<<dim3(18, 32), 512, 0, stream>>>(xb, wb, qo, ko, vto);
    attn_fwd<<<dim3(96, 8), 256, 0, stream>>>(qo, ko, vto, ao);
    gemm_proj<<<dim3(6, 64), 256, 0, stream>>>(ao, wpb, bp, out);
}